// Round 2
// baseline (7976.957 us; speedup 1.0000x reference)
//
#include <hip/hip_runtime.h>
#include <hip/hip_bf16.h>

typedef unsigned int u32;

__device__ __forceinline__ float sigf(float x){ return 1.0f/(1.0f + __expf(-x)); }

// ---------------------------------------------------------------------------
// ws layout (float offsets)
//   gi     : [2560][768]
//   hf     : [1280][256]
//   hb     : [1280][256]
//   x1     : [128][30][30]
//   x2     : [64][14][14]
//   x_img  : [64][6][6]
//   ak_in  : [768]
//   prev_sum[512], next_sum[512]
// total ~11.0 MB
// ---------------------------------------------------------------------------
#define GI_OFF   0
#define GI_SZ    (2560*768)
#define HF_OFF   (GI_OFF + GI_SZ)
#define HF_SZ    (1280*256)
#define HB_OFF   (HF_OFF + HF_SZ)
#define X1_OFF   (HB_OFF + HF_SZ)
#define X1_SZ    (128*30*30)
#define X2_OFF   (X1_OFF + X1_SZ)
#define X2_SZ    (64*14*14)
#define XIMG_OFF (X2_OFF + X2_SZ)
#define XIMG_SZ  (64*6*6)
#define AKIN_OFF (XIMG_OFF + XIMG_SZ)
#define PSUM_OFF (AKIN_OFF + 768)
#define NSUM_OFF (PSUM_OFF + 512)

// ---------------- gi precompute: gi[row][768] = emb[tok] @ wih[j].T + bih[j] ----
__global__ __launch_bounds__(256) void gi_kernel(
    const float* __restrict__ emb, const float* __restrict__ wih_all,
    const float* __restrict__ bih_all,
    const int* __restrict__ prev, const int* __restrict__ curr, const int* __restrict__ nxt,
    float* __restrict__ gi_all)
{
  const int offs[7] = {0,512,768,1280,1792,2048,2560};
  int row0 = blockIdx.x * 16;
  int j = 0;
  while (row0 >= offs[j+1]) ++j;
  int t0 = row0 - offs[j];
  int sel = j % 3;
  const int* inst = (sel==0)? prev : (sel==1)? curr : nxt;

  __shared__ __align__(16) float e[16][32];
  int u = threadIdx.x;
  for (int idx=u; idx<512; idx+=256){
    int r = idx >> 5, k = idx & 31;
    e[r][k] = emb[(size_t)inst[t0+r]*32 + k];
  }
  __syncthreads();

  const float* wih = wih_all + (size_t)j*768*32;
  const float* bih = bih_all + (size_t)j*768;
  for (int g3=0; g3<3; ++g3){
    int o = g3*256 + u;
    float bb = bih[o];
    float acc[16];
#pragma unroll
    for (int r=0;r<16;++r) acc[r]=bb;
    const float* wr = wih + (size_t)o*32;
#pragma unroll
    for (int k=0;k<32;++k){
      float w = wr[k];
#pragma unroll
      for (int r=0;r<16;++r) acc[r] += w * e[r][k];
    }
    for (int r=0;r<16;++r) gi_all[(size_t)(row0+r)*768 + o] = acc[r];
  }
}

// ---------------- GRU sequential scan: 6 blocks, one per GRU -------------------
// 768 threads: thread u owns whh row u (256 f32 in registers).
__global__ __launch_bounds__(768,1) void gru_scan_kernel(
    const float* __restrict__ whh_all, const float* __restrict__ bhh_all,
    const float* __restrict__ gi_all, float* __restrict__ hf, float* __restrict__ hb)
{
  const int lens[6] = {512,256,512,512,256,512};
  const int offs[6] = {0,512,768,1280,1792,2048};
  int j = blockIdx.x;
  int u = threadIdx.x;
  int len = lens[j];
  const float* gi = gi_all + (size_t)offs[j]*768;
  float* outp = ((j<3)? hf : hb) + (size_t)offs[j%3]*256;

  // register-cache row u of whh[j]
  float4 w4[64];
  {
    const float4* wp = (const float4*)(whh_all + ((size_t)j*768 + u)*256);
#pragma unroll
    for (int i=0;i<64;++i) w4[i] = wp[i];
  }
  float bh = bhh_all[j*768 + u];

  __shared__ __align__(16) float hsh[256];
  __shared__ float gacc[768];
  if (u < 256) hsh[u] = 0.0f;
  __syncthreads();

  for (int t=0; t<len; ++t){
    // prefetch gi row for this step (used after barrier; loads issue early)
    float gr=0.f, gz=0.f, gn=0.f;
    if (u < 256){
      const float* git = gi + (size_t)t*768;
      gr = git[u]; gz = git[256+u]; gn = git[512+u];
    }
    // a = w_row . h   (4 independent accumulator chains)
    float a0=0.f, a1=0.f, a2=0.f, a3=0.f;
    const float4* hv4 = (const float4*)hsh;
#pragma unroll
    for (int i=0;i<64;++i){
      float4 hv = hv4[i];
      float4 ww = w4[i];
      a0 += ww.x*hv.x; a1 += ww.y*hv.y; a2 += ww.z*hv.z; a3 += ww.w*hv.w;
    }
    gacc[u] = bh + ((a0+a1)+(a2+a3));
    __syncthreads();
    if (u < 256){
      float r  = sigf(gr + gacc[u]);
      float z  = sigf(gz + gacc[256+u]);
      float n  = tanhf(gn + r*gacc[512+u]);
      float h2 = (1.0f - z)*n + z*hsh[u];
      outp[(size_t)t*256 + u] = h2;
      hsh[u] = h2;
    }
    __syncthreads();
  }
}

// ---------------- convs (direct, one thread per output) ------------------------
__global__ __launch_bounds__(256) void conv1_kernel(
    const float* __restrict__ x, const float* __restrict__ w, const float* __restrict__ b,
    float* __restrict__ y)
{
  int idx = blockIdx.x*256 + threadIdx.x;
  if (idx >= 128*30*30) return;
  int c = idx/900, rem = idx%900, i = rem/30, jx = rem%30;
  float acc = b[c];
  const float* wc = w + (size_t)c*3*8*8;
  for (int ic=0; ic<3; ++ic)
    for (int ky=0; ky<8; ++ky){
      const float* xrow = x + ((size_t)ic*124 + (i*4+ky))*124 + jx*4;
      const float* wrow = wc + (ic*8+ky)*8;
#pragma unroll
      for (int kx=0; kx<8; ++kx) acc += xrow[kx] * wrow[kx];
    }
  y[idx] = fmaxf(acc, 0.0f);
}

__global__ __launch_bounds__(256) void conv2_kernel(
    const float* __restrict__ x1, const float* __restrict__ w, const float* __restrict__ b,
    float* __restrict__ y)
{
  int idx = blockIdx.x*256 + threadIdx.x;
  if (idx >= 64*14*14) return;
  int c = idx/196, rem = idx%196, i = rem/14, jx = rem%14;
  float acc = b[c];
  for (int ic=0; ic<128; ++ic){
    const float* xc = x1 + (size_t)ic*900;
    const float* wc = w + ((size_t)c*128 + ic)*16;
#pragma unroll
    for (int ky=0; ky<4; ++ky)
#pragma unroll
      for (int kx=0; kx<4; ++kx)
        acc += xc[(i*2+ky)*30 + (jx*2+kx)] * wc[ky*4+kx];
  }
  y[idx] = fmaxf(acc, 0.0f);
}

__global__ __launch_bounds__(256) void conv3_kernel(
    const float* __restrict__ x2, const float* __restrict__ w, const float* __restrict__ b,
    float* __restrict__ y)
{
  int idx = blockIdx.x*256 + threadIdx.x;
  if (idx >= 64*6*6) return;
  int c = idx/36, rem = idx%36, i = rem/6, jx = rem%6;
  float acc = b[c];
  for (int ic=0; ic<64; ++ic){
    const float* xc = x2 + (size_t)ic*196;
    const float* wc = w + ((size_t)c*64 + ic)*16;
#pragma unroll
    for (int ky=0; ky<4; ++ky)
#pragma unroll
      for (int kx=0; kx<4; ++kx)
        acc += xc[(i*2+ky)*14 + (jx*2+kx)] * wc[ky*4+kx];
  }
  y[idx] = fmaxf(acc, 0.0f);
}

// ---------------- image embedding + ak_in assembly -----------------------------
__global__ __launch_bounds__(256) void imgemb_kernel(
    const float* __restrict__ x_img, const float* __restrict__ img_w, const float* __restrict__ img_b,
    const float* __restrict__ hf, const float* __restrict__ hb, float* __restrict__ ak_in)
{
  __shared__ __align__(16) float xs[2304];
  int u = threadIdx.x;
  for (int i=u; i<2304; i+=256) xs[i] = x_img[i];
  __syncthreads();
  float a0=0.f,a1=0.f,a2=0.f,a3=0.f;
  const float4* wr = (const float4*)(img_w + (size_t)u*2304);
  const float4* xv = (const float4*)xs;
  for (int k=0; k<576; ++k){
    float4 w = wr[k], xx = xv[k];
    a0 += w.x*xx.x; a1 += w.y*xx.y; a2 += w.z*xx.z; a3 += w.w*xx.w;
  }
  ak_in[512+u] = img_b[u] + ((a0+a1)+(a2+a3)); // image_emb
  ak_in[u]     = hf[(size_t)767*256+u];        // curr_rep fwd half
  ak_in[256+u] = hb[(size_t)767*256+u];        // curr_rep bwd half (rb[P])
}

// ---------------- attention (block 0 = prev, block 1 = next) -------------------
__global__ __launch_bounds__(512) void attend_kernel(
    const float* __restrict__ ak_in_g,
    const float* __restrict__ akp_w, const float* __restrict__ akp_b,
    const float* __restrict__ akn_w, const float* __restrict__ akn_b,
    const float* __restrict__ bil_p_w, const float* __restrict__ bil_p_b,
    const float* __restrict__ bil_n_w, const float* __restrict__ bil_n_b,
    const float* __restrict__ hf, const float* __restrict__ hb,
    float* __restrict__ prev_sum, float* __restrict__ next_sum)
{
  int blk = blockIdx.x;
  const float* akw = blk? akn_w : akp_w;
  const float* akb = blk? akn_b : akp_b;
  const float* bw  = blk? bil_n_w : bil_p_w;
  float bb         = blk? bil_n_b[0] : bil_p_b[0];
  float* outp      = blk? next_sum : prev_sum;

  int u = threadIdx.x;
  __shared__ __align__(16) float ak[768];
  __shared__ __align__(16) float kk[256];
  __shared__ __align__(16) float q[512];
  __shared__ float s[512], red[512];

  for (int i=u; i<768; i+=512) ak[i] = ak_in_g[i];
  __syncthreads();

  if (u < 256){
    float a0=0.f,a1=0.f,a2=0.f,a3=0.f;
    const float4* wr = (const float4*)(akw + (size_t)u*768);
    const float4* av = (const float4*)ak;
    for (int m=0; m<192; ++m){
      float4 w = wr[m], aa = av[m];
      a0 += w.x*aa.x; a1 += w.y*aa.y; a2 += w.z*aa.z; a3 += w.w*aa.w;
    }
    kk[u] = akb[u] + ((a0+a1)+(a2+a3));
  }
  __syncthreads();

  { // q = k @ bw[0]   (coalesced: lane u reads column u)
    float acc = 0.0f;
    for (int m=0; m<256; ++m) acc += kk[m]*bw[(size_t)m*512 + u];
    q[u] = acc;
  }
  __syncthreads();

  { // scores: s[i] = q . rep[i] + bb
    int i = u;
    const float4* repf = (const float4*)(hf + (size_t)(blk? (768+i) : i)*256);
    const float4* repb = (const float4*)(hb + (size_t)(blk? (511-i) : (1279-i))*256);
    const float4* qf = (const float4*)q;
    float a0=0.f,a1=0.f;
    for (int v=0; v<64; ++v){
      float4 qq = qf[v],  rr = repf[v];
      a0 += qq.x*rr.x + qq.y*rr.y + qq.z*rr.z + qq.w*rr.w;
      float4 q2 = qf[64+v], r2 = repb[v];
      a1 += q2.x*r2.x + q2.y*r2.y + q2.z*r2.z + q2.w*r2.w;
    }
    s[u] = bb + a0 + a1;
  }
  __syncthreads();

  // softmax over 512
  red[u] = s[u]; __syncthreads();
  for (int st=256; st>0; st>>=1){ if (u<st) red[u]=fmaxf(red[u],red[u+st]); __syncthreads(); }
  float mx = red[0]; __syncthreads();
  float ex = __expf(s[u]-mx);
  red[u] = ex; __syncthreads();
  for (int st=256; st>0; st>>=1){ if (u<st) red[u]+=red[u+st]; __syncthreads(); }
  float inv = 1.0f/red[0]; __syncthreads();
  s[u] = ex*inv;
  __syncthreads();

  // weighted sum over rows (coalesced: lane reads column u)
  float o = 0.0f;
  if (u < 256){
    for (int r=0; r<512; ++r){
      const float* rf = hf + (size_t)(blk? (768+r) : r)*256;
      o += s[r]*rf[u];
    }
    outp[u] = o;
  } else {
    int v = u-256;
    for (int r=0; r<512; ++r){
      const float* rb = hb + (size_t)(blk? (511-r) : (1279-r))*256;
      o += s[r]*rb[v];
    }
    outp[u] = o;
  }
}

// ---------------- head: pred/nred, gate, lin, LSTM, outputs --------------------
__global__ __launch_bounds__(1024) void head_kernel(
    const float* __restrict__ prev_sum_g, const float* __restrict__ next_sum_g,
    const float* __restrict__ ak_in_g, const float* __restrict__ x_img,
    const float* __restrict__ pred_w, const float* __restrict__ pred_b,
    const float* __restrict__ nred_w, const float* __restrict__ nred_b,
    const float* __restrict__ gate_w, const float* __restrict__ gate_b,
    const float* __restrict__ lin_w,  const float* __restrict__ lin_b,
    const float* __restrict__ lstm_wih, const float* __restrict__ lstm_whh,
    const float* __restrict__ lstm_bih, const float* __restrict__ lstm_bhh,
    const float* __restrict__ hx, const float* __restrict__ cx,
    const int* __restrict__ tx, const float* __restrict__ time_emb,
    const float* __restrict__ crit_w, const float* __restrict__ crit_b,
    const float* __restrict__ act_w,  const float* __restrict__ act_b,
    float* __restrict__ out)
{
  int u = threadIdx.x;
  __shared__ __align__(16) float ps[512];
  __shared__ __align__(16) float ns[512];
  __shared__ __align__(16) float cr[512];
  __shared__ float pg[64], ng[64], gate[64];
  __shared__ __align__(16) float xg[2304];
  __shared__ __align__(16) float feat[256];
  __shared__ __align__(16) float hxs[256];
  __shared__ float g[1024], cxs[256], z[288];

  if (u < 512){ ps[u]=prev_sum_g[u]; ns[u]=next_sum_g[u]; cr[u]=ak_in_g[u]; }
  if (u >= 512 && u < 768){ int t=u-512; hxs[t]=hx[t]; cxs[t]=cx[t]; }
  for (int i=u; i<2304; i+=1024) xg[i] = x_img[i];
  __syncthreads();

  if (u < 64){
    float a = pred_b[u];
    const float* wr = pred_w + (size_t)u*512;
    for (int k=0;k<512;++k) a += ps[k]*wr[k];
    pg[u] = a;
  } else if (u < 128){
    int t = u-64;
    float a = nred_b[t];
    const float* wr = nred_w + (size_t)t*512;
    for (int k=0;k<512;++k) a += ns[k]*wr[k];
    ng[t] = a;
  }
  __syncthreads();

  if (u < 64){
    float a = gate_b[u];
    const float* wr = gate_w + (size_t)u*640;
    for (int k=0;k<512;++k) a += cr[k]*wr[k];
    for (int k=0;k<64;++k)  a += pg[k]*wr[512+k];
    for (int k=0;k<64;++k)  a += ng[k]*wr[576+k];
    gate[u] = sigf(a);
  }
  __syncthreads();

  for (int i=u; i<2304; i+=1024) xg[i] *= gate[i/36];
  __syncthreads();

  if (u < 256){
    float a0=0.f,a1=0.f,a2=0.f,a3=0.f;
    const float4* wr = (const float4*)(lin_w + (size_t)u*2304);
    const float4* xv = (const float4*)xg;
    for (int k=0;k<576;++k){
      float4 w = wr[k], xx = xv[k];
      a0 += w.x*xx.x; a1 += w.y*xx.y; a2 += w.z*xx.z; a3 += w.w*xx.w;
    }
    feat[u] = fmaxf(lin_b[u] + ((a0+a1)+(a2+a3)), 0.0f);
  }
  __syncthreads();

  {
    float a0=0.f,a1=0.f;
    const float4* w1 = (const float4*)(lstm_wih + (size_t)u*256);
    const float4* w2 = (const float4*)(lstm_whh + (size_t)u*256);
    const float4* fv = (const float4*)feat;
    const float4* hv = (const float4*)hxs;
    for (int k=0;k<64;++k){
      float4 wa = w1[k], fa = fv[k];
      a0 += wa.x*fa.x + wa.y*fa.y + wa.z*fa.z + wa.w*fa.w;
      float4 wb = w2[k], ha = hv[k];
      a1 += wb.x*ha.x + wb.y*ha.y + wb.z*ha.z + wb.w*ha.w;
    }
    g[u] = lstm_bih[u] + lstm_bhh[u] + a0 + a1;
  }
  __syncthreads();

  if (u < 256){
    float ii=g[u], ff=g[256+u], gg=g[512+u], oo=g[768+u];
    float c2 = sigf(ff)*cxs[u] + sigf(ii)*tanhf(gg);
    float h2 = sigf(oo)*tanhf(c2);
    z[u] = h2;
    out[5+u]   = h2;
    out[261+u] = c2;
  }
  if (u >= 256 && u < 288){
    int e2 = u-256;
    z[u] = time_emb[(size_t)tx[0]*32 + e2];
  }
  __syncthreads();

  if (u == 0){
    float a = crit_b[0];
    for (int k=0;k<288;++k) a += z[k]*crit_w[k];
    out[0] = a;
  } else if (u < 5){
    int r = u-1;
    float a = act_b[r];
    for (int k=0;k<288;++k) a += z[k]*act_w[(size_t)r*288+k];
    out[1+r] = a;
  }
}

// ---------------------------------------------------------------------------
extern "C" void kernel_launch(void* const* d_in, const int* in_sizes, int n_in,
                              void* d_out, int out_size, void* d_ws, size_t ws_size,
                              hipStream_t stream)
{
  const float* x        = (const float*)d_in[0];
  const float* hx       = (const float*)d_in[1];
  const float* cx       = (const float*)d_in[2];
  const int*  prev      = (const int*)d_in[3];
  const int*  curr      = (const int*)d_in[4];
  const int*  nxt       = (const int*)d_in[5];
  const int*  tx        = (const int*)d_in[6];
  const float* emb      = (const float*)d_in[7];
  const float* gru_wih  = (const float*)d_in[8];
  const float* gru_whh  = (const float*)d_in[9];
  const float* gru_bih  = (const float*)d_in[10];
  const float* gru_bhh  = (const float*)d_in[11];
  const float* conv1_w  = (const float*)d_in[12];
  const float* conv1_b  = (const float*)d_in[13];
  const float* conv2_w  = (const float*)d_in[14];
  const float* conv2_b  = (const float*)d_in[15];
  const float* conv3_w  = (const float*)d_in[16];
  const float* conv3_b  = (const float*)d_in[17];
  const float* img_w    = (const float*)d_in[18];
  const float* img_b    = (const float*)d_in[19];
  const float* akp_w    = (const float*)d_in[20];
  const float* akp_b    = (const float*)d_in[21];
  const float* akn_w    = (const float*)d_in[22];
  const float* akn_b    = (const float*)d_in[23];
  const float* bil_p_w  = (const float*)d_in[24];
  const float* bil_p_b  = (const float*)d_in[25];
  const float* bil_n_w  = (const float*)d_in[26];
  const float* bil_n_b  = (const float*)d_in[27];
  const float* pred_w   = (const float*)d_in[28];
  const float* pred_b   = (const float*)d_in[29];
  const float* nred_w   = (const float*)d_in[30];
  const float* nred_b   = (const float*)d_in[31];
  const float* gate_w   = (const float*)d_in[32];
  const float* gate_b   = (const float*)d_in[33];
  const float* lin_w    = (const float*)d_in[34];
  const float* lin_b    = (const float*)d_in[35];
  const float* lstm_wih = (const float*)d_in[36];
  const float* lstm_whh = (const float*)d_in[37];
  const float* lstm_bih = (const float*)d_in[38];
  const float* lstm_bhh = (const float*)d_in[39];
  const float* time_emb = (const float*)d_in[40];
  const float* crit_w   = (const float*)d_in[41];
  const float* crit_b   = (const float*)d_in[42];
  const float* act_w    = (const float*)d_in[43];
  const float* act_b    = (const float*)d_in[44];

  float* ws = (float*)d_ws;
  float* gi    = ws + GI_OFF;
  float* hf    = ws + HF_OFF;
  float* hb    = ws + HB_OFF;
  float* x1    = ws + X1_OFF;
  float* x2    = ws + X2_OFF;
  float* ximg  = ws + XIMG_OFF;
  float* akin  = ws + AKIN_OFF;
  float* psum  = ws + PSUM_OFF;
  float* nsum  = ws + NSUM_OFF;

  float* out = (float*)d_out;

  gi_kernel      <<<160, 256, 0, stream>>>(emb, gru_wih, gru_bih, prev, curr, nxt, gi);
  gru_scan_kernel<<<6,   768, 0, stream>>>(gru_whh, gru_bhh, gi, hf, hb);
  conv1_kernel   <<<450, 256, 0, stream>>>(x, conv1_w, conv1_b, x1);
  conv2_kernel   <<<49,  256, 0, stream>>>(x1, conv2_w, conv2_b, x2);
  conv3_kernel   <<<9,   256, 0, stream>>>(x2, conv3_w, conv3_b, ximg);
  imgemb_kernel  <<<1,   256, 0, stream>>>(ximg, img_w, img_b, hf, hb, akin);
  attend_kernel  <<<2,   512, 0, stream>>>(akin, akp_w, akp_b, akn_w, akn_b,
                                           bil_p_w, bil_p_b, bil_n_w, bil_n_b,
                                           hf, hb, psum, nsum);
  head_kernel    <<<1,  1024, 0, stream>>>(psum, nsum, akin, ximg,
                                           pred_w, pred_b, nred_w, nred_b,
                                           gate_w, gate_b, lin_w, lin_b,
                                           lstm_wih, lstm_whh, lstm_bih, lstm_bhh,
                                           hx, cx, tx, time_emb,
                                           crit_w, crit_b, act_w, act_b, out);
}